// Round 8
// baseline (272.193 us; speedup 1.0000x reference)
//
#include <hip/hip_runtime.h>
#include <hip/hip_cooperative_groups.h>

#define NROW 327680            // 256*256*5
#define NCLS 80
#define K_TARGET 1024u
#define CAP 2048u
#define MAXN 2048
#define MAX_OUT 100
#define NBIN 864               // score in (0.01,1): bits>>16 in [0x3C23, 0x3F80)
#define BIN0 0x3C23
#define DEC_BLOCKS 1280        // NROW / 256
#define ADJW 32                // 2048 bits = 32 ull per adjacency row
#define ADJC_ROWS 128          // adjacency rows cached in LDS for the greedy scan

// ---------------- workspace layout (bytes) ----------------
#define WS_SCORES 0            // float[NROW]          1,310,720
#define WS_PART   1310720      // uint[1280*864]       4,423,680
#define WS_HIST   5734400      // uint[1024]               4,096
#define WS_CNT    5738496      // uint[16]                    64
#define WS_KEYS   5738560      // ull[MAXN]               16,384
#define WS_SORT   5754944      // ull[MAXN]               16,384
#define WS_CBOX   5771328      // float4[MAXN]            32,768
#define WS_ADJ    5804096      // ull[MAXN*ADJW]         524,288

typedef float f4v __attribute__((ext_vector_type(4)));
typedef f4v f4u __attribute__((aligned(4)));   // 4B-aligned float4 load
typedef unsigned long long ull;

// ---------------------------------------------------------------------------
// Kernel 1: decode (R7's proven VGPR-resident score path) + fused per-block
// LDS histogram -> part[block][bin], non-atomic global writes.
// Score op-order identical to R1-R7 (absmax 0.0).
// ---------------------------------------------------------------------------
__global__ __launch_bounds__(256, 1) void decode_hist(
    const float* __restrict__ x, float* __restrict__ scores,
    unsigned* __restrict__ part) {
  __shared__ unsigned h[NBIN];
  const int t = threadIdx.x;
  for (int i = t; i < NBIN; i += 256) h[i] = 0;
  __syncthreads();

  const int r = blockIdx.x * 256 + t;
  const float* rp = x + (size_t)r * 85;

  float conf_l = rp[4];
  float cl[80];
  #pragma unroll
  for (int c = 0; c < 20; ++c) {           // floats 5..84 = exactly 20 x vec4
    f4v t4 = *(const f4u*)(rp + 5 + 4 * c);
    cl[4*c+0] = t4.x; cl[4*c+1] = t4.y; cl[4*c+2] = t4.z; cl[4*c+3] = t4.w;
  }
  float m = cl[0];
  #pragma unroll
  for (int c = 1; c < NCLS; ++c) { float l = cl[c]; if (l > m) m = l; }
  float s = 0.f;
  #pragma unroll
  for (int c = 0; c < NCLS; ++c) s += expf(cl[c] - m);
  float conf = 1.f / (1.f + expf(-conf_l));
  float best = conf * (1.f / s);
  float score = (best > 0.01f) ? best : 0.f;
  scores[r] = score;

  if (score > 0.f) {
    int idx = (int)(__float_as_uint(score) >> 16) - BIN0;
    if (idx > NBIN - 1) idx = NBIN - 1;
    atomicAdd(&h[idx], 1u);               // LDS atomic only
  }
  __syncthreads();
  unsigned* pb = part + (size_t)blockIdx.x * NBIN;
  for (int i = t; i < NBIN; i += 256) pb[i] = h[i];
}

// ---------------------------------------------------------------------------
// Kernel 2 (cooperative, 80 blocks x 1024): everything after decode.
// grid.sync() replaces 5 kernel boundaries. Phase logic verbatim from the
// absmax-0.0 R7 pipeline.
// ---------------------------------------------------------------------------
__global__ __launch_bounds__(1024) void coop_kernel(
    const float* __restrict__ x, const float* __restrict__ anchors,
    const float* __restrict__ scores, const unsigned* __restrict__ part,
    unsigned* __restrict__ hist, unsigned* __restrict__ cnt,
    ull* __restrict__ keys, ull* __restrict__ sorted,
    float4* __restrict__ cboxs, ull* __restrict__ adj,
    float* __restrict__ out) {
  cooperative_groups::grid_group gg = cooperative_groups::this_grid();
  const int t = threadIdx.x;
  const int b = blockIdx.x;
  const int wv = t >> 6, lane = t & 63;

  __shared__ unsigned bufA[1024], bufB[1024];
  __shared__ unsigned TshL, blocal, bbase;
  __shared__ ull lk[MAXN];                  // 16 KB
  __shared__ ull adjc[ADJC_ROWS * ADJW];    // 32 KB (block 0's greedy cache)
  __shared__ int keptcc[MAX_OUT];
  __shared__ int kcls[MAX_OUT];
  __shared__ int knum;

  // ---- P0: zero hist + cnt (ws is poisoned 0xAA every call) ----
  if (b == 0) { if (t < NBIN) hist[t] = 0u; if (t < 2) cnt[t] = 0u; }
  gg.sync();

  // ---- P1: accumulate 16 decode-block partials per coop block ----
  if (t < NBIN) {
    unsigned s = 0;
    #pragma unroll
    for (int k = 0; k < 16; ++k)
      s += part[(size_t)(b * 16 + k) * NBIN + t];
    if (s) atomicAdd(&hist[t], s);
  }
  gg.sync();

  // ---- P2: replicated suffix-scan threshold (identical T in every block) ----
  bufA[t] = (t < NBIN) ? hist[t] : 0u;
  __syncthreads();
  unsigned* src = bufA; unsigned* dst = bufB;
  for (int d = 1; d < 1024; d <<= 1) {
    unsigned val = src[t] + ((t + d < 1024) ? src[t + d] : 0u);
    dst[t] = val;
    __syncthreads();
    unsigned* tmp = src; src = dst; dst = tmp;
  }
  if (src[t] >= K_TARGET && (t == 1023 || src[t + 1] < K_TARGET)) {
    unsigned TT = (unsigned)t;
    if (src[t] > CAP) TT += 1;            // residual sfx[t+1] < K_TARGET <= CAP
    TshL = TT;
  }
  if (t == 0 && src[0] < K_TARGET) TshL = 0;
  __syncthreads();
  const unsigned T = TshL;

  // ---- P3: compact (one float4 per thread; 80*1024 == NROW/4 exactly) ----
  if (t == 0) blocal = 0;
  __syncthreads();
  {
    const int gi = b * 1024 + t;
    float4 s4 = ((const float4*)scores)[gi];
    float sv[4] = {s4.x, s4.y, s4.z, s4.w};
    ull lkk[4]; int nl = 0;
    #pragma unroll
    for (int k = 0; k < 4; ++k) {
      float s = sv[k];
      if (s <= 0.f) continue;
      unsigned bits = __float_as_uint(s);
      int idx = (int)(bits >> 16) - BIN0;
      if (idx > NBIN - 1) idx = NBIN - 1;
      if ((unsigned)idx < T) continue;
      unsigned r = (unsigned)(gi * 4 + k);
      lkk[nl++] = ((ull)bits << 32) | (ull)(0xFFFFFFFFu - r);
    }
    unsigned lpos = nl ? atomicAdd(&blocal, (unsigned)nl) : 0u;
    __syncthreads();
    if (t == 0 && blocal) bbase = atomicAdd(&cnt[0], blocal);
    __syncthreads();
    if (nl) {
      unsigned base = bbase + lpos;
      for (int i2 = 0; i2 < nl; ++i2)
        if (base + i2 < CAP) keys[base + i2] = lkk[i2];
    }
  }
  gg.sync();

  unsigned n = cnt[0]; if (n > CAP) n = CAP;

  // ---- P4a: wave-parallel rank + sorted scatter + candidate box decode ----
  for (unsigned i = t; i < n; i += 1024) lk[i] = keys[i];
  __syncthreads();
  for (unsigned i = b * 16u + wv; i < n; i += 1280u) {
    ull ki = lk[i];
    unsigned rk = 0;
    for (unsigned j = lane; j < n; j += 64) rk += (lk[j] > ki) ? 1u : 0u;
    #pragma unroll
    for (int d2 = 32; d2 >= 1; d2 >>= 1) rk += __shfl_xor((int)rk, d2, 64);
    if (lane == 0) {
      sorted[rk] = ki;
      unsigned r = 0xFFFFFFFFu - (unsigned)(ki & 0xFFFFFFFFull);
      const float* rp = x + (size_t)r * 85;
      float tx = rp[0], ty = rp[1], tw = rp[2], th = rp[3];
      const int a  = (int)(r % 5u);
      const int hw = (int)(r / 5u);
      const float wf = (float)(hw & 255);
      const float hf = (float)(hw >> 8);
      float sx = 1.f / (1.f + expf(-tx));
      float sy = 1.f / (1.f + expf(-ty));
      float xc = (sx + wf) / 256.f;
      float yc = (sy + hf) / 256.f;
      float bw = expf(tw) * anchors[2*a]     / 256.f;
      float bh = expf(th) * anchors[2*a + 1] / 256.f;
      float hwd = bw / 2.f, hhd = bh / 2.f;
      cboxs[rk] = make_float4(xc - hwd, yc - hhd, xc + hwd, yc + hhd);
    }
  }
  gg.sync();

  // ---- P4b: adjacency bitmap in sorted space, wave per row ----
  for (unsigned i = b * 16u + wv; i < n; i += 1280u) {
    float4 bi = cboxs[i];
    float areai = (bi.z - bi.x) * (bi.w - bi.y);
    for (unsigned it = 0; it < ADJW; ++it) {
      unsigned j = it * 64u + lane;
      bool sup = false;
      if (j < n) {
        float4 bj = cboxs[j];
        float xx1 = fmaxf(bi.x, bj.x), yy1 = fmaxf(bi.y, bj.y);
        float xx2 = fminf(bi.z, bj.z), yy2 = fminf(bi.w, bj.w);
        float inter = fmaxf(xx2 - xx1, 0.f) * fmaxf(yy2 - yy1, 0.f);
        float areaj = (bj.z - bj.x) * (bj.w - bj.y);
        float uni = areai + areaj - inter;
        float iou = (uni > 0.f) ? (inter / uni) : 0.f;
        sup = iou > 0.5f;
      }
      ull mm = __ballot(sup);
      if (lane == 0) adj[(size_t)i * ADJW + it] = mm;
    }
  }
  gg.sync();

  // ---- P5: block 0 only — greedy bitmask scan + class argmax + output ----
  if (b != 0) return;

  if (t == 0) knum = 0;
  for (unsigned i = t; i < n; i += 1024) lk[i] = sorted[i];
  const unsigned ncache = (n < ADJC_ROWS ? n : ADJC_ROWS) * ADJW;
  for (unsigned i = t; i < ncache; i += 1024) adjc[i] = adj[i];
  __syncthreads();

  if (t < 64) {
    ull mask = 0ull;
    int nk = 0;
    ull rA = 0ull, rB = 0ull;
    if (lane < ADJW) {
      if (n > 0) rA = adjc[0 * ADJW + lane];
      if (n > 1) rB = (1 < ADJC_ROWS) ? adjc[1 * ADJW + lane]
                                      : adj[1 * ADJW + lane];
    }
    for (unsigned cc = 0; cc < n; ++cc) {
      ull rC = 0ull;
      unsigned pcc = cc + 2;
      if (lane < ADJW && pcc < n)
        rC = (pcc < ADJC_ROWS) ? adjc[pcc * ADJW + lane]
                               : adj[(size_t)pcc * ADJW + lane];
      const int w = (int)(cc >> 6);
      ull mw = (ull)__shfl((long long)mask, w, 64);
      bool sup = (mw >> (cc & 63u)) & 1ull;
      if (!sup) {
        mask |= rA;                       // row cc (self bit harmless)
        if (lane == 0) keptcc[nk] = (int)cc;
        ++nk;
        if (nk == MAX_OUT) break;
      }
      rA = rB; rB = rC;
    }
    if (lane == 0) knum = nk;
  }
  __syncthreads();
  const int kn = knum;

  // wave-parallel class argmax (R6/R7-proven packing & first-max tie-break)
  for (int kidx = wv; kidx < kn; kidx += 16) {
    ull key = lk[keptcc[kidx]];
    unsigned r = 0xFFFFFFFFu - (unsigned)(key & 0xFFFFFFFFull);
    const float* rp = x + (size_t)r * 85;
    float l0 = rp[5 + lane];
    unsigned b0 = __float_as_uint(l0);
    b0 = (b0 & 0x80000000u) ? ~b0 : (b0 | 0x80000000u);
    ull kv = ((ull)b0 << 32) | (ull)(0xFFFFFFFFu - lane);
    if (lane < 16) {
      float l1 = rp[5 + 64 + lane];
      unsigned b1 = __float_as_uint(l1);
      b1 = (b1 & 0x80000000u) ? ~b1 : (b1 | 0x80000000u);
      ull kv1 = ((ull)b1 << 32) | (ull)(0xFFFFFFFFu - (64 + lane));
      if (kv1 > kv) kv = kv1;
    }
    #pragma unroll
    for (int d3 = 32; d3 >= 1; d3 >>= 1) {
      ull o = (ull)__shfl_xor((long long)kv, d3, 64);
      if (o > kv) kv = o;
    }
    if (lane == 0)
      kcls[kidx] = (int)(0xFFFFFFFFu - (unsigned)(kv & 0xFFFFFFFFull));
  }
  __syncthreads();

  // outputs: [0..99] conf, [100..499] boxes (100,4), [500..599] classes
  if (t < MAX_OUT) {
    float conf = 0.f; float4 bb = make_float4(0.f, 0.f, 0.f, 0.f); float cf = -1.f;
    if (t < kn) {
      int cc = keptcc[t];
      ull key = lk[cc];
      conf = __uint_as_float((unsigned)(key >> 32));
      bb = cboxs[cc];
      cf = (float)kcls[t];
    }
    out[t] = conf;
    ((float4*)(out + 100))[t] = bb;
    out[500 + t] = cf;
  }
}

// ---------------------------------------------------------------------------
extern "C" void kernel_launch(void* const* d_in, const int* in_sizes, int n_in,
                              void* d_out, int out_size, void* d_ws, size_t ws_size,
                              hipStream_t stream) {
  const float* x       = (const float*)d_in[0];
  const float* anchors = (const float*)d_in[1];
  float* out = (float*)d_out;
  char* ws = (char*)d_ws;

  float*    scores = (float*)(ws + WS_SCORES);
  unsigned* part   = (unsigned*)(ws + WS_PART);
  unsigned* hist   = (unsigned*)(ws + WS_HIST);
  unsigned* cnt    = (unsigned*)(ws + WS_CNT);
  ull*      keys   = (ull*)(ws + WS_KEYS);
  ull*      sorted = (ull*)(ws + WS_SORT);
  float4*   cboxs  = (float4*)(ws + WS_CBOX);
  ull*      adj    = (ull*)(ws + WS_ADJ);

  hipLaunchKernelGGL(decode_hist, dim3(DEC_BLOCKS), dim3(256),
                     0, stream, x, scores, part);

  void* kargs[] = { (void*)&x, (void*)&anchors, (void*)&scores, (void*)&part,
                    (void*)&hist, (void*)&cnt, (void*)&keys, (void*)&sorted,
                    (void*)&cboxs, (void*)&adj, (void*)&out };
  hipLaunchCooperativeKernel((void*)coop_kernel, dim3(80), dim3(1024),
                             kargs, 0, stream);
}